// Round 5
// baseline (1280.041 us; speedup 1.0000x reference)
//
#include <hip/hip_runtime.h>
#include <math.h>

#define V_NODES 3000
#define K_DEG 16
#define E_EDGES 48000
#define H 256
#define TE 128
#define L_LAYERS 12

typedef __attribute__((ext_vector_type(4))) float f32x4;
typedef __attribute__((ext_vector_type(8))) __bf16 bf16x8;
typedef __attribute__((ext_vector_type(4))) unsigned short u16x4;

__device__ __forceinline__ unsigned short f2bf(float f) {
  unsigned u = __float_as_uint(f);
  unsigned r = (u + 0x7fffu + ((u >> 16) & 1u)) >> 16;
  return (unsigned short)r;
}

__device__ __forceinline__ void gload16(const void* g, void* l) {
  __builtin_amdgcn_global_load_lds((const __attribute__((address_space(1))) void*)g,
                                   (__attribute__((address_space(3))) void*)l, 16, 0, 0);
}

// ---------------------------------------------------------------------------
// Weight prep: transpose 256x256 f32 [k][n] -> bf16 [n][k]; UVAB packed to
// [1024][256] per layer.
// ---------------------------------------------------------------------------
__global__ __launch_bounds__(256) void k_prep_w(const float* __restrict__ U_w, const float* __restrict__ V_w,
                                                const float* __restrict__ A_w, const float* __restrict__ B_w,
                                                const float* __restrict__ C_w, const float* __restrict__ plo_w,
                                                const float* __restrict__ edge_w,
                                                unsigned short* __restrict__ WT4, unsigned short* __restrict__ WTC,
                                                unsigned short* __restrict__ WTplo, unsigned short* __restrict__ WTedge) {
  int bid = blockIdx.x;
  const float* src;
  unsigned short* dst;
  int tt;
  if (bid < 768) {
    int l = bid >> 6;
    int rem = bid & 63;
    int mat = rem >> 4;
    tt = rem & 15;
    const float* srcs[4] = {U_w, V_w, A_w, B_w};
    src = srcs[mat] + (size_t)l * H * H;
    dst = WT4 + (size_t)l * 1024 * H + (size_t)mat * H * H;
  } else if (bid < 960) {
    int b2 = bid - 768;
    int l = b2 >> 4;
    tt = b2 & 15;
    src = C_w + (size_t)l * H * H;
    dst = WTC + (size_t)l * H * H;
  } else if (bid < 1152) {
    int b2 = bid - 960;
    int l = b2 >> 4;
    tt = b2 & 15;
    src = plo_w + (size_t)l * H * H;
    dst = WTplo + (size_t)l * H * H;
  } else {
    tt = bid - 1152;
    src = edge_w;
    dst = WTedge;
  }
  int k0 = (tt & 3) * 64, n0 = (tt >> 2) * 64;
  __shared__ float ts[64][65];
  int c = threadIdx.x & 63;
  int r0 = threadIdx.x >> 6;
  for (int rr = 0; rr < 64; rr += 4) {
    int r = rr + r0;
    ts[r][c] = src[(size_t)(k0 + r) * H + n0 + c];
  }
  __syncthreads();
  for (int nn = 0; nn < 64; nn += 4) {
    int n = nn + r0;
    dst[(size_t)(n0 + n) * H + k0 + c] = f2bf(ts[c][n]);
  }
}

__global__ __launch_bounds__(256) void k_prep_b(const float* __restrict__ U_b, const float* __restrict__ V_b,
                                                const float* __restrict__ A_b, const float* __restrict__ B_b,
                                                float* __restrict__ b4) {
  int l = blockIdx.x;
  int t = threadIdx.x;
  b4[l * 1024 + 0 + t] = U_b[l * H + t];
  b4[l * 1024 + 256 + t] = V_b[l * H + t];
  b4[l * 1024 + 512 + t] = A_b[l * H + t];
  b4[l * 1024 + 768 + t] = B_b[l * H + t];
}

// ---------------------------------------------------------------------------
// Plain MFMA GEMM (128x128 tile, 4 waves, BK=64).
// MODE 0: node UVAB -> out_f32[m*1024+n] = acc + bias[n]
// MODE 3: edge embed -> acc + bias + mask_emb[mask[m]]; write e f32 + bf16
// ---------------------------------------------------------------------------
template <int MODE>
__global__ __launch_bounds__(256) void k_gemm(const unsigned short* __restrict__ A,
                                              const unsigned short* __restrict__ WT,
                                              int M,
                                              const float* __restrict__ bias,
                                              const int* __restrict__ maskp,
                                              const float* __restrict__ mask_emb,
                                              float* __restrict__ out_f32,
                                              unsigned short* __restrict__ out_bf16) {
  const int t = threadIdx.x;
  const int m0 = blockIdx.x * 128;
  const int nb = blockIdx.y * 128;
  const int lane = t & 63;
  const int wave = t >> 6;
  const int wr = wave >> 1, wc = wave & 1;
  const int lrow = lane & 15, lg = lane >> 4;

  __shared__ __align__(16) char lds[32768];
  char* Als = lds;
  char* Bls = lds + 16384;

  f32x4 acc[4][4];
#pragma unroll
  for (int i = 0; i < 4; ++i)
#pragma unroll
    for (int j = 0; j < 4; ++j) acc[i][j] = (f32x4)0.0f;

  for (int kt = 0; kt < 4; ++kt) {
    const int k0b = kt * 128;
#pragma unroll
    for (int i = 0; i < 4; ++i) {
      int o = i * 4096 + t * 16;
      int row = o >> 7;
      int cb = o & 127;
      int cbl = cb ^ ((row & 7) << 4);
      int rA = m0 + row;
      rA = rA < M ? rA : 0;
      gload16((const char*)A + (size_t)rA * 512 + k0b + cbl,
              Als + i * 4096 + (t & 192) * 16);
      gload16((const char*)WT + (size_t)(nb + row) * 512 + k0b + cbl,
              Bls + i * 4096 + (t & 192) * 16);
    }
    __syncthreads();
#pragma unroll
    for (int ks = 0; ks < 2; ++ks) {
      bf16x8 af[4], bfv[4];
#pragma unroll
      for (int mi = 0; mi < 4; ++mi) {
        int ra = wr * 64 + mi * 16 + lrow;
        int cba = (ks * 64 + lg * 16) ^ ((ra & 7) << 4);
        af[mi] = *(const bf16x8*)(Als + ra * 128 + cba);
        int rb = wc * 64 + mi * 16 + lrow;
        int cbb = (ks * 64 + lg * 16) ^ ((rb & 7) << 4);
        bfv[mi] = *(const bf16x8*)(Bls + rb * 128 + cbb);
      }
#pragma unroll
      for (int mi = 0; mi < 4; ++mi)
#pragma unroll
        for (int ni = 0; ni < 4; ++ni)
          acc[mi][ni] = __builtin_amdgcn_mfma_f32_16x16x32_bf16(af[mi], bfv[ni], acc[mi][ni], 0, 0, 0);
    }
    __syncthreads();
  }

#pragma unroll
  for (int mi = 0; mi < 4; ++mi) {
#pragma unroll
    for (int r = 0; r < 4; ++r) {
      int m = m0 + wr * 64 + mi * 16 + lg * 4 + r;
      if (MODE == 0 && m >= M) continue;
      int mk = 0;
      if constexpr (MODE == 3) { mk = maskp[m]; }
#pragma unroll
      for (int ni = 0; ni < 4; ++ni) {
        int n = nb + wc * 64 + ni * 16 + lrow;
        float v = acc[mi][ni][r] + bias[n];
        if constexpr (MODE == 0) {
          out_f32[(size_t)m * 1024 + n] = v;
        } else {
          v += mask_emb[mk * 256 + n];
          out_f32[(size_t)m * 256 + n] = v;
          out_bf16[(size_t)m * 256 + n] = f2bf(v);
        }
      }
    }
  }
}

// ---------------------------------------------------------------------------
// Fully-fused layer kernel: per block = 64 edges = 4 nodes.
// G1: e_new = e_bf@C_w (+Cb) -> enew LDS (Ah/Bh deferred)
// E1: node update (reads enew + XW coalesced, + Ah/Bh at read point)
// E2: double-LN+silu chain (+ Ah/Bh at read point) -> bout bf16 regs -> LDS
// G2: plo = bout@WTplo (staged per-K-strip into upper 32KB)
// E3: e += plo + bias (via LDS transpose); write e f32 + e_bf bf16
// GN: (last layer) per-block channel sum/sumsq -> f64 atomics
// ---------------------------------------------------------------------------
__global__ __launch_bounds__(512, 4) void k_mega(const unsigned short* __restrict__ A,
                                                 const unsigned short* __restrict__ WTC_l,
                                                 const unsigned short* __restrict__ WTplo_l,
                                                 const float* __restrict__ Cb,
                                                 const float* __restrict__ pb2,
                                                 const int* __restrict__ ei_col,
                                                 const float* __restrict__ XW,
                                                 const float* __restrict__ nhg, const float* __restrict__ nhb,
                                                 const float* __restrict__ neg_, const float* __restrict__ neb_,
                                                 const float* __restrict__ tvec_l,
                                                 const float* __restrict__ pg_, const float* __restrict__ pb_,
                                                 float* __restrict__ x, unsigned short* __restrict__ xb,
                                                 float* __restrict__ e, unsigned short* __restrict__ e_bf,
                                                 double* __restrict__ gn_sums) {
  const int t = threadIdx.x;
  const int m0 = blockIdx.x * 64;
  const int lane = t & 63;
  const int wave = t >> 6;
  const int wr = wave >> 2, wc = wave & 3;  // 2 x 4 wave grid: 32 rows x 64 cols
  const int lrow = lane & 15, lg = lane >> 4;
  const int c0 = lane * 4;

  __shared__ __align__(16) char lds[65536];
  char* Als = lds;            // [64][128B] swizzled (G1)
  char* Bls = lds + 8192;     // [256][128B] swizzled (G1)
  float* enew = (float*)lds;  // [64][256] f32 swizzled (E0..E2, E3)
  // G2: bout bf16 [64][512B] swizzled @0..32KB ; WTplo strip [256][128B] @32..64KB

  const int wave_off = wave * 1024;

  // ================= G1: C-GEMM =================
  f32x4 acc[2][4];
#pragma unroll
  for (int i = 0; i < 2; ++i)
#pragma unroll
    for (int j = 0; j < 4; ++j) acc[i][j] = (f32x4)0.0f;

  for (int kt = 0; kt < 4; ++kt) {
    const int k0b = kt * 128;
    {
      int o = t * 16;
      int row = o >> 7;
      int cbl = (o & 127) ^ ((row & 7) << 4);
      gload16((const char*)A + (size_t)(m0 + row) * 512 + k0b + cbl, Als + wave_off);
    }
#pragma unroll
    for (int c = 0; c < 4; ++c) {
      int o = c * 8192 + t * 16;
      int row = o >> 7;
      int cbl = (o & 127) ^ ((row & 7) << 4);
      gload16((const char*)WTC_l + (size_t)row * 512 + k0b + cbl, Bls + c * 8192 + wave_off);
    }
    __syncthreads();
#pragma unroll
    for (int ks = 0; ks < 2; ++ks) {
      bf16x8 af[2], bfv[4];
#pragma unroll
      for (int mi = 0; mi < 2; ++mi) {
        int ra = wr * 32 + mi * 16 + lrow;
        af[mi] = *(const bf16x8*)(Als + ra * 128 + ((ks * 64 + lg * 16) ^ ((ra & 7) << 4)));
      }
#pragma unroll
      for (int ni = 0; ni < 4; ++ni) {
        int rb = wc * 64 + ni * 16 + lrow;
        bfv[ni] = *(const bf16x8*)(Bls + rb * 128 + ((ks * 64 + lg * 16) ^ ((rb & 7) << 4)));
      }
#pragma unroll
      for (int mi = 0; mi < 2; ++mi)
#pragma unroll
        for (int ni = 0; ni < 4; ++ni)
          acc[mi][ni] = __builtin_amdgcn_mfma_f32_16x16x32_bf16(af[mi], bfv[ni], acc[mi][ni], 0, 0, 0);
    }
    __syncthreads();
  }

  // ================= E0: acc + Cb -> enew (swizzled); Ah/Bh deferred =======
  {
    float bs[4];
#pragma unroll
    for (int ni = 0; ni < 4; ++ni) bs[ni] = Cb[wc * 64 + ni * 16 + lrow];
#pragma unroll
    for (int mi = 0; mi < 2; ++mi) {
#pragma unroll
      for (int r = 0; r < 4; ++r) {
        int ml = wr * 32 + mi * 16 + lg * 4 + r;
        int sw = (ml & 15) << 2;
#pragma unroll
        for (int ni = 0; ni < 4; ++ni) {
          int n = wc * 64 + ni * 16 + lrow;
          enew[ml * 256 + (n ^ sw)] = acc[mi][ni][r] + bs[ni];
        }
      }
    }
  }
  __syncthreads();

  // ================= E1: node update (waves 0-3) ===========================
  if (wave < 4) {
    int v = (m0 >> 4) + wave;
    f32x4 bh = *(const f32x4*)&XW[(size_t)v * 1024 + 768 + c0];  // Bh[v], hoisted
    f32x4 agg = (f32x4)0.0f;
#pragma unroll 4
    for (int k = 0; k < K_DEG; ++k) {
      int row = wave * 16 + k;
      int cv = ei_col[m0 + row];
      f32x4 en = *(const f32x4*)&enew[row * 256 + (c0 ^ ((row & 15) << 2))];
      f32x4 ah = *(const f32x4*)&XW[(size_t)cv * 1024 + 512 + c0];
      f32x4 vh = *(const f32x4*)&XW[(size_t)cv * 1024 + 256 + c0];
#pragma unroll
      for (int i = 0; i < 4; ++i) {
        float env = en[i] + ah[i] + bh[i];
        agg[i] += vh[i] / (1.0f + expf(-env));
      }
    }
    f32x4 s4 = *(const f32x4*)&XW[(size_t)v * 1024 + c0];  // Uh
    s4 += agg;
    float s = s4[0] + s4[1] + s4[2] + s4[3];
    float sq = s4[0] * s4[0] + s4[1] * s4[1] + s4[2] * s4[2] + s4[3] * s4[3];
#pragma unroll
    for (int st = 1; st < 64; st <<= 1) { s += __shfl_xor(s, st); sq += __shfl_xor(sq, st); }
    float mean = s * (1.0f / H);
    float inv = rsqrtf(sq * (1.0f / H) - mean * mean + 1e-5f);
    f32x4 g = *(const f32x4*)&nhg[c0];
    f32x4 bb = *(const f32x4*)&nhb[c0];
    f32x4 xo = *(const f32x4*)&x[(size_t)v * H + c0];
    u16x4 ov;
#pragma unroll
    for (int i = 0; i < 4; ++i) {
      float h = fmaxf((s4[i] - mean) * inv * g[i] + bb[i], 0.0f);
      xo[i] += h;
      ov[i] = f2bf(xo[i]);
    }
    *(f32x4*)&x[(size_t)v * H + c0] = xo;
    *(u16x4*)&xb[(size_t)v * H + c0] = ov;
  }

  // ================= E2: double-LN + silu -> bout regs =====================
  const int nrows = (wave < 4) ? 6 : 10;
  const int rbase = (wave < 4) ? 40 + wave * 6 : (wave - 4) * 10;
  u16x4 ovr[10];
  {
    f32x4 g1 = *(const f32x4*)&neg_[c0];
    f32x4 b1 = *(const f32x4*)&neb_[c0];
    f32x4 tv = *(const f32x4*)&tvec_l[c0];
    f32x4 g2 = *(const f32x4*)&pg_[c0];
    f32x4 b2 = *(const f32x4*)&pb_[c0];
#pragma unroll
    for (int k = 0; k < 10; ++k) {
      if (k < nrows) {
        int row = rbase + k;
        int m = m0 + row;
        int cv = ei_col[m];
        int nv = m >> 4;
        f32x4 vv = *(const f32x4*)&enew[row * 256 + (c0 ^ ((row & 15) << 2))];
        f32x4 ah = *(const f32x4*)&XW[(size_t)cv * 1024 + 512 + c0];
        f32x4 bh = *(const f32x4*)&XW[(size_t)nv * 1024 + 768 + c0];
#pragma unroll
        for (int i = 0; i < 4; ++i) vv[i] = vv[i] + ah[i] + bh[i];
        float s = vv[0] + vv[1] + vv[2] + vv[3];
        float sq = vv[0] * vv[0] + vv[1] * vv[1] + vv[2] * vv[2] + vv[3] * vv[3];
#pragma unroll
        for (int st = 1; st < 64; st <<= 1) { s += __shfl_xor(s, st); sq += __shfl_xor(sq, st); }
        float mean = s * (1.0f / H);
        float inv = rsqrtf(sq * (1.0f / H) - mean * mean + 1e-5f);
        f32x4 a;
#pragma unroll
        for (int i = 0; i < 4; ++i) a[i] = fmaxf((vv[i] - mean) * inv * g1[i] + b1[i], 0.0f) + tv[i];
        s = a[0] + a[1] + a[2] + a[3];
        sq = a[0] * a[0] + a[1] * a[1] + a[2] * a[2] + a[3] * a[3];
#pragma unroll
        for (int st = 1; st < 64; st <<= 1) { s += __shfl_xor(s, st); sq += __shfl_xor(sq, st); }
        mean = s * (1.0f / H);
        inv = rsqrtf(sq * (1.0f / H) - mean * mean + 1e-5f);
#pragma unroll
        for (int i = 0; i < 4; ++i) {
          float n = (a[i] - mean) * inv * g2[i] + b2[i];
          ovr[k][i] = f2bf(n / (1.0f + expf(-n)));
        }
      }
    }
  }
  __syncthreads();  // all enew reads (E1+E2) done

  // bout regs -> LDS [0,32KB) swizzled; rows are 512B, XOR within 128B blocks
#pragma unroll
  for (int k = 0; k < 10; ++k) {
    if (k < nrows) {
      int row = rbase + k;
      *(u16x4*)(lds + row * 512 + ((lane * 8) ^ ((row & 7) << 4))) = ovr[k];
    }
  }

  // ================= G2: plo-GEMM (bout @ WTplo) ===========================
  f32x4 acc2[2][4];
#pragma unroll
  for (int i = 0; i < 2; ++i)
#pragma unroll
    for (int j = 0; j < 4; ++j) acc2[i][j] = (f32x4)0.0f;

  for (int kt = 0; kt < 4; ++kt) {
    const int k0b = kt * 128;
#pragma unroll
    for (int c = 0; c < 4; ++c) {
      int o = c * 8192 + t * 16;
      int row = o >> 7;
      int cbl = (o & 127) ^ ((row & 7) << 4);
      gload16((const char*)WTplo_l + (size_t)row * 512 + k0b + cbl, lds + 32768 + c * 8192 + wave_off);
    }
    __syncthreads();
#pragma unroll
    for (int ks = 0; ks < 2; ++ks) {
      bf16x8 af2[2], bv2[4];
#pragma unroll
      for (int mi = 0; mi < 2; ++mi) {
        int ra = wr * 32 + mi * 16 + lrow;
        af2[mi] = *(const bf16x8*)(lds + ra * 512 + kt * 128 + ((ks * 64 + lg * 16) ^ ((ra & 7) << 4)));
      }
#pragma unroll
      for (int ni = 0; ni < 4; ++ni) {
        int rb = wc * 64 + ni * 16 + lrow;
        bv2[ni] = *(const bf16x8*)(lds + 32768 + rb * 128 + ((ks * 64 + lg * 16) ^ ((rb & 7) << 4)));
      }
#pragma unroll
      for (int mi = 0; mi < 2; ++mi)
#pragma unroll
        for (int ni = 0; ni < 4; ++ni)
          acc2[mi][ni] = __builtin_amdgcn_mfma_f32_16x16x32_bf16(af2[mi], bv2[ni], acc2[mi][ni], 0, 0, 0);
    }
    __syncthreads();
  }

  // ================= E3: e += plo + bias ===================================
  {
    float pb2s[4];
#pragma unroll
    for (int ni = 0; ni < 4; ++ni) pb2s[ni] = pb2[wc * 64 + ni * 16 + lrow];
#pragma unroll
    for (int mi = 0; mi < 2; ++mi) {
#pragma unroll
      for (int r = 0; r < 4; ++r) {
        int ml = wr * 32 + mi * 16 + lg * 4 + r;
        int sw = (ml & 15) << 2;
#pragma unroll
        for (int ni = 0; ni < 4; ++ni) {
          int n = wc * 64 + ni * 16 + lrow;
          enew[ml * 256 + (n ^ sw)] = acc2[mi][ni][r] + pb2s[ni];
        }
      }
    }
  }
  __syncthreads();

  float gs0 = 0, gs1 = 0, gs2 = 0, gs3 = 0, gq0 = 0, gq1 = 0, gq2 = 0, gq3 = 0;
#pragma unroll
  for (int k = 0; k < 8; ++k) {
    int row = wave * 8 + k;
    int m = m0 + row;
    f32x4 dv = *(const f32x4*)&enew[row * 256 + (c0 ^ ((row & 15) << 2))];
    f32x4 eo = *(const f32x4*)&e[(size_t)m * 256 + c0];
    f32x4 en2;
    u16x4 ob;
#pragma unroll
    for (int i = 0; i < 4; ++i) {
      en2[i] = eo[i] + dv[i];
      ob[i] = f2bf(en2[i]);
    }
    *(f32x4*)&e[(size_t)m * 256 + c0] = en2;
    *(u16x4*)&e_bf[(size_t)m * 256 + c0] = ob;
    if (gn_sums) {
      gs0 += en2[0]; gq0 += en2[0] * en2[0];
      gs1 += en2[1]; gq1 += en2[1] * en2[1];
      gs2 += en2[2]; gq2 += en2[2] * en2[2];
      gs3 += en2[3]; gq3 += en2[3] * en2[3];
    }
  }

  // ================= GN partial reduce (last layer only) ===================
  if (gn_sums) {
    __syncthreads();  // enew reads done before reusing LDS
    double* redS = (double*)lds;            // [8][256] f64 = 16KB
    double* redQ = (double*)(lds + 16384);  // 16KB
    redS[wave * 256 + c0 + 0] = gs0; redS[wave * 256 + c0 + 1] = gs1;
    redS[wave * 256 + c0 + 2] = gs2; redS[wave * 256 + c0 + 3] = gs3;
    redQ[wave * 256 + c0 + 0] = gq0; redQ[wave * 256 + c0 + 1] = gq1;
    redQ[wave * 256 + c0 + 2] = gq2; redQ[wave * 256 + c0 + 3] = gq3;
    __syncthreads();
    if (t < 256) {
      double s = 0, q = 0;
#pragma unroll
      for (int w = 0; w < 8; ++w) { s += redS[w * 256 + t]; q += redQ[w * 256 + t]; }
      atomicAdd(&gn_sums[t], s);
      atomicAdd(&gn_sums[H + t], q);
    }
  }
}

// ---------------------------------------------------------------------------
// Node positional embedding + node_w matmul
// ---------------------------------------------------------------------------
__global__ __launch_bounds__(256) void k_node_embed(const float* __restrict__ coords,
                                                    const float* __restrict__ W,
                                                    const float* __restrict__ b,
                                                    float* __restrict__ x,
                                                    unsigned short* __restrict__ xb) {
  int v = blockIdx.x;
  int j = threadIdx.x;
  __shared__ float4 pe4[H / 4];
  float cy = coords[v * 2 + 0] * 6.283185307179586f;
  float cx = coords[v * 2 + 1] * 6.283185307179586f;
  int idx = j & 127;
  float coord = (j < 128) ? cy : cx;
  float dim_t = powf(10000.0f, (2.0f * (float)(idx >> 1)) / 128.0f);
  float val = coord / dim_t;
  ((float*)pe4)[j] = (idx & 1) ? cosf(val) : sinf(val);
  __syncthreads();
  float acc = b[j];
  for (int k4 = 0; k4 < H / 4; ++k4) {
    float4 p = pe4[k4];
    int k = 4 * k4;
    acc += p.x * W[(k + 0) * H + j] + p.y * W[(k + 1) * H + j] +
           p.z * W[(k + 2) * H + j] + p.w * W[(k + 3) * H + j];
  }
  x[(size_t)v * H + j] = acc;
  xb[(size_t)v * H + j] = f2bf(acc);
}

// ---------------------------------------------------------------------------
// Edge scalar sine embedding -> pe bf16
// ---------------------------------------------------------------------------
__global__ __launch_bounds__(256) void k_pe(const float* __restrict__ e_vals, unsigned short* __restrict__ pe) {
  int eid = blockIdx.x * 4 + (threadIdx.x >> 6);
  int lane = threadIdx.x & 63;
  int c0 = lane * 4;
  float val = e_vals[eid];
  const float lg = 13.287712379549449f / 256.0f;
  u16x4 ov;
#pragma unroll
  for (int i = 0; i < 4; ++i) {
    int c = c0 + i;
    float invd = exp2f(-(float)(c & ~1) * lg);
    float arg = val * invd;
    float s = (c & 1) ? cosf(arg) : sinf(arg);
    ov[i] = f2bf(s);
  }
  *(u16x4*)&pe[(size_t)eid * H + c0] = ov;
}

// ---------------------------------------------------------------------------
// Timestep embedding MLP + per-layer conditioning
// ---------------------------------------------------------------------------
__global__ __launch_bounds__(256) void k_temb(const int* __restrict__ t,
                                              const float* __restrict__ te1_w, const float* __restrict__ te1_b,
                                              const float* __restrict__ te2_w, const float* __restrict__ te2_b,
                                              float* __restrict__ temb_out) {
  __shared__ float emb[H];
  __shared__ float h1[TE];
  int j = threadIdx.x;
  float tv = (float)t[0];
  {
    int i = j & 127;
    float f = expf(-logf(10000.0f) * (float)i / 128.0f);
    float arg = tv * f;
    emb[j] = (j < 128) ? cosf(arg) : sinf(arg);
  }
  __syncthreads();
  if (j < TE) {
    float acc = te1_b[j];
    for (int k = 0; k < H; ++k) acc += emb[k] * te1_w[k * TE + j];
    h1[j] = fmaxf(acc, 0.0f);
  }
  __syncthreads();
  if (j < TE) {
    float acc = te2_b[j];
    for (int k = 0; k < TE; ++k) acc += h1[k] * te2_w[k * TE + j];
    temb_out[j] = acc;
  }
}

__global__ __launch_bounds__(256) void k_tvec(const float* __restrict__ temb,
                                              const float* __restrict__ tl_w, const float* __restrict__ tl_b,
                                              float* __restrict__ tvec) {
  int l = blockIdx.x;
  int j = threadIdx.x;
  __shared__ float rt[TE];
  if (j < TE) rt[j] = fmaxf(temb[j], 0.0f);
  __syncthreads();
  float acc = tl_b[l * H + j];
  for (int k = 0; k < TE; ++k) acc += rt[k] * tl_w[(size_t)(l * TE + k) * H + j];
  tvec[l * H + j] = acc;
}

__global__ void k_gn_finalize(const double* __restrict__ sums, float* __restrict__ gstats) {
  int g = threadIdx.x;
  if (g < 32) {
    double s = 0.0, sq = 0.0;
    for (int c = g * 8; c < g * 8 + 8; ++c) {
      s += sums[c];
      sq += sums[H + c];
    }
    double n = 8.0 * (double)E_EDGES;
    double mean = s / n;
    double var = sq / n - mean * mean;
    gstats[g] = (float)mean;
    gstats[32 + g] = (float)(1.0 / sqrt(var + 1e-5));
  }
}

__global__ __launch_bounds__(256) void k_head(const float* __restrict__ e,
                                              const float* __restrict__ gstats,
                                              const float* __restrict__ gn_g, const float* __restrict__ gn_b,
                                              const float* __restrict__ out_w, const float* __restrict__ out_b,
                                              float* __restrict__ out) {
  int wv = threadIdx.x >> 6;
  int lane = threadIdx.x & 63;
  int eid = blockIdx.x * 4 + wv;
  int c0 = lane * 4;
  float4 ev = *(const float4*)&e[(size_t)eid * H + c0];
  float vv[4] = {ev.x, ev.y, ev.z, ev.w};
  float a0 = 0.0f, a1 = 0.0f;
#pragma unroll
  for (int i = 0; i < 4; ++i) {
    int c = c0 + i;
    int g = c >> 3;
    float v = (vv[i] - gstats[g]) * gstats[32 + g] * gn_g[c] + gn_b[c];
    v = fmaxf(v, 0.0f);
    a0 += v * out_w[c * 2 + 0];
    a1 += v * out_w[c * 2 + 1];
  }
  for (int s = 32; s > 0; s >>= 1) {
    a0 += __shfl_down(a0, s);
    a1 += __shfl_down(a1, s);
  }
  if (lane == 0) {
    out[(size_t)eid * 2 + 0] = a0 + out_b[0];
    out[(size_t)eid * 2 + 1] = a1 + out_b[1];
  }
}

// ---------------------------------------------------------------------------
extern "C" void kernel_launch(void* const* d_in, const int* in_sizes, int n_in,
                              void* d_out, int out_size, void* d_ws, size_t ws_size,
                              hipStream_t stream) {
  const float* nodes_feature = (const float*)d_in[0];
  const float* e_vals = (const float*)d_in[1];
  const int* mask = (const int*)d_in[2];
  const int* t = (const int*)d_in[3];
  const int* edge_index = (const int*)d_in[4];
  const float* node_w = (const float*)d_in[5];
  const float* node_b = (const float*)d_in[6];
  const float* edge_w = (const float*)d_in[7];
  const float* edge_b = (const float*)d_in[8];
  const float* te1_w = (const float*)d_in[9];
  const float* te1_b = (const float*)d_in[10];
  const float* te2_w = (const float*)d_in[11];
  const float* te2_b = (const float*)d_in[12];
  const float* U_w = (const float*)d_in[13];
  const float* U_b = (const float*)d_in[14];
  const float* V_w = (const float*)d_in[15];
  const float* V_b = (const float*)d_in[16];
  const float* A_w = (const float*)d_in[17];
  const float* A_b = (const float*)d_in[18];
  const float* B_w = (const float*)d_in[19];
  const float* B_b = (const float*)d_in[20];
  const float* C_w = (const float*)d_in[21];
  const float* C_b = (const float*)d_in[22];
  const float* nh_g = (const float*)d_in[23];
  const float* nh_b = (const float*)d_in[24];
  const float* ne_g = (const float*)d_in[25];
  const float* ne_b = (const float*)d_in[26];
  const float* tl_w = (const float*)d_in[27];
  const float* tl_b = (const float*)d_in[28];
  const float* plo_g = (const float*)d_in[29];
  const float* plo_b = (const float*)d_in[30];
  const float* plo_w = (const float*)d_in[31];
  const float* plo_b2 = (const float*)d_in[32];
  const float* gn_g = (const float*)d_in[33];
  const float* gn_b = (const float*)d_in[34];
  const float* out_w = (const float*)d_in[35];
  const float* out_b = (const float*)d_in[36];
  const float* mask_emb = (const float*)d_in[37];

  char* wsb = (char*)d_ws;
  size_t off = 0;
  auto alloc = [&](size_t bytes) -> void* {
    void* p = wsb + off;
    off += (bytes + 255) & ~(size_t)255;
    return p;
  };
  double* gn_sums = (double*)alloc(512 * sizeof(double));
  float* XW = (float*)alloc((size_t)V_NODES * 1024 * 4);
  float* e = (float*)alloc((size_t)E_EDGES * H * 4);
  unsigned short* e_bf = (unsigned short*)alloc((size_t)E_EDGES * H * 2);
  unsigned short* pe_b = (unsigned short*)alloc((size_t)E_EDGES * H * 2);
  unsigned short* x_bf = (unsigned short*)alloc((size_t)V_NODES * H * 2);
  unsigned short* WT4 = (unsigned short*)alloc((size_t)L_LAYERS * 1024 * H * 2);
  unsigned short* WTC = (unsigned short*)alloc((size_t)L_LAYERS * H * H * 2);
  unsigned short* WTplo = (unsigned short*)alloc((size_t)L_LAYERS * H * H * 2);
  unsigned short* WTedge = (unsigned short*)alloc((size_t)H * H * 2);
  float* b4 = (float*)alloc((size_t)L_LAYERS * 1024 * 4);
  float* temb = (float*)alloc(TE * 4);
  float* tvec = (float*)alloc((size_t)L_LAYERS * H * 4);
  float* gstats = (float*)alloc(64 * 4);

  const int* ei_col = edge_index + E_EDGES;

  float* x = (float*)d_out;
  float* out2 = (float*)d_out + (size_t)V_NODES * H;

  k_prep_w<<<1168, 256, 0, stream>>>(U_w, V_w, A_w, B_w, C_w, plo_w, edge_w, WT4, WTC, WTplo, WTedge);
  k_prep_b<<<L_LAYERS, 256, 0, stream>>>(U_b, V_b, A_b, B_b, b4);
  k_node_embed<<<V_NODES, 256, 0, stream>>>(nodes_feature, node_w, node_b, x, x_bf);
  k_pe<<<E_EDGES / 4, 256, 0, stream>>>(e_vals, pe_b);
  k_temb<<<1, 256, 0, stream>>>(t, te1_w, te1_b, te2_w, te2_b, temb);
  k_tvec<<<L_LAYERS, 256, 0, stream>>>(temb, tl_w, tl_b, tvec);
  k_gemm<3><<<dim3(E_EDGES / 128, 2), 256, 0, stream>>>(pe_b, WTedge, E_EDGES, edge_b, mask, mask_emb, e, e_bf);
  hipMemsetAsync(gn_sums, 0, 512 * sizeof(double), stream);

  for (int l = 0; l < L_LAYERS; ++l) {
    size_t wo = (size_t)l * H * H;
    size_t bo = (size_t)l * H;
    k_gemm<0><<<dim3(24, 8), 256, 0, stream>>>(x_bf, WT4 + (size_t)l * 1024 * H, V_NODES, b4 + l * 1024,
                                               nullptr, nullptr, XW, nullptr);
    k_mega<<<E_EDGES / 64, 512, 0, stream>>>(e_bf, WTC + wo, WTplo + wo, C_b + bo, plo_b2 + bo, ei_col, XW,
                                             nh_g + bo, nh_b + bo, ne_g + bo, ne_b + bo, tvec + bo,
                                             plo_g + bo, plo_b + bo, x, x_bf, e, e_bf,
                                             (l == L_LAYERS - 1) ? gn_sums : nullptr);
  }

  k_gn_finalize<<<1, 64, 0, stream>>>(gn_sums, gstats);
  k_head<<<E_EDGES / 4, 256, 0, stream>>>(e, gstats, gn_g, gn_b, out_w, out_b, out2);
}

// Round 6
// 984.432 us; speedup vs baseline: 1.3003x; 1.3003x over previous
//
#include <hip/hip_runtime.h>
#include <math.h>

#define V_NODES 3000
#define K_DEG 16
#define E_EDGES 48000
#define H 256
#define TE 128
#define L_LAYERS 12

typedef __attribute__((ext_vector_type(4))) float f32x4;
typedef __attribute__((ext_vector_type(8))) __bf16 bf16x8;
typedef __attribute__((ext_vector_type(4))) unsigned short u16x4;

__device__ __forceinline__ unsigned short f2bf(float f) {
  unsigned u = __float_as_uint(f);
  unsigned r = (u + 0x7fffu + ((u >> 16) & 1u)) >> 16;
  return (unsigned short)r;
}

// fast sigmoid: 1/(1+2^(-x*log2e)) via v_exp_f32 + v_rcp_f32 (~1e-6 rel err)
__device__ __forceinline__ float fsig(float x) {
  return __builtin_amdgcn_rcpf(1.0f + __builtin_amdgcn_exp2f(-1.4426950408889634f * x));
}

__device__ __forceinline__ void gload16(const void* g, void* l) {
  __builtin_amdgcn_global_load_lds((const __attribute__((address_space(1))) void*)g,
                                   (__attribute__((address_space(3))) void*)l, 16, 0, 0);
}

// ---------------------------------------------------------------------------
// Weight prep: transpose 256x256 f32 [k][n] -> bf16 [n][k]; UVAB packed to
// [1024][256] per layer.
// ---------------------------------------------------------------------------
__global__ __launch_bounds__(256) void k_prep_w(const float* __restrict__ U_w, const float* __restrict__ V_w,
                                                const float* __restrict__ A_w, const float* __restrict__ B_w,
                                                const float* __restrict__ C_w, const float* __restrict__ plo_w,
                                                const float* __restrict__ edge_w,
                                                unsigned short* __restrict__ WT4, unsigned short* __restrict__ WTC,
                                                unsigned short* __restrict__ WTplo, unsigned short* __restrict__ WTedge) {
  int bid = blockIdx.x;
  const float* src;
  unsigned short* dst;
  int tt;
  if (bid < 768) {
    int l = bid >> 6;
    int rem = bid & 63;
    int mat = rem >> 4;
    tt = rem & 15;
    const float* srcs[4] = {U_w, V_w, A_w, B_w};
    src = srcs[mat] + (size_t)l * H * H;
    dst = WT4 + (size_t)l * 1024 * H + (size_t)mat * H * H;
  } else if (bid < 960) {
    int b2 = bid - 768;
    int l = b2 >> 4;
    tt = b2 & 15;
    src = C_w + (size_t)l * H * H;
    dst = WTC + (size_t)l * H * H;
  } else if (bid < 1152) {
    int b2 = bid - 960;
    int l = b2 >> 4;
    tt = b2 & 15;
    src = plo_w + (size_t)l * H * H;
    dst = WTplo + (size_t)l * H * H;
  } else {
    tt = bid - 1152;
    src = edge_w;
    dst = WTedge;
  }
  int k0 = (tt & 3) * 64, n0 = (tt >> 2) * 64;
  __shared__ float ts[64][65];
  int c = threadIdx.x & 63;
  int r0 = threadIdx.x >> 6;
  for (int rr = 0; rr < 64; rr += 4) {
    int r = rr + r0;
    ts[r][c] = src[(size_t)(k0 + r) * H + n0 + c];
  }
  __syncthreads();
  for (int nn = 0; nn < 64; nn += 4) {
    int n = nn + r0;
    dst[(size_t)(n0 + n) * H + k0 + c] = f2bf(ts[c][n]);
  }
}

__global__ __launch_bounds__(256) void k_prep_b(const float* __restrict__ U_b, const float* __restrict__ V_b,
                                                const float* __restrict__ A_b, const float* __restrict__ B_b,
                                                float* __restrict__ b4) {
  int l = blockIdx.x;
  int t = threadIdx.x;
  b4[l * 1024 + 0 + t] = U_b[l * H + t];
  b4[l * 1024 + 256 + t] = V_b[l * H + t];
  b4[l * 1024 + 512 + t] = A_b[l * H + t];
  b4[l * 1024 + 768 + t] = B_b[l * H + t];
}

// ---------------------------------------------------------------------------
// Plain MFMA GEMM (128x128 tile, 4 waves, BK=64).
// MODE 0: node UVAB -> out_f32[m*1024+n] = acc + bias[n]
// MODE 2: edge plo  -> e += acc + bias; write e f32 + bf16; GN: fused stats
// MODE 3: edge embed-> acc + bias + mask_emb[mask[m]]; write e f32 + bf16
// ---------------------------------------------------------------------------
template <int MODE, bool GN>
__global__ __launch_bounds__(256) void k_gemm(const unsigned short* __restrict__ A,
                                              const unsigned short* __restrict__ WT,
                                              int M,
                                              const float* __restrict__ bias,
                                              const int* __restrict__ maskp,
                                              const float* __restrict__ mask_emb,
                                              float* __restrict__ out_f32,
                                              unsigned short* __restrict__ out_bf16,
                                              double* __restrict__ gnp) {
  const int t = threadIdx.x;
  const int m0 = blockIdx.x * 128;
  const int nb = blockIdx.y * 128;
  const int lane = t & 63;
  const int wave = t >> 6;
  const int wr = wave >> 1, wc = wave & 1;
  const int lrow = lane & 15, lg = lane >> 4;

  __shared__ __align__(16) char lds[32768];
  char* Als = lds;
  char* Bls = lds + 16384;

  f32x4 acc[4][4];
#pragma unroll
  for (int i = 0; i < 4; ++i)
#pragma unroll
    for (int j = 0; j < 4; ++j) acc[i][j] = (f32x4)0.0f;

  for (int kt = 0; kt < 4; ++kt) {
    const int k0b = kt * 128;
#pragma unroll
    for (int i = 0; i < 4; ++i) {
      int o = i * 4096 + t * 16;
      int row = o >> 7;
      int cb = o & 127;
      int cbl = cb ^ ((row & 7) << 4);
      int rA = m0 + row;
      rA = rA < M ? rA : 0;
      gload16((const char*)A + (size_t)rA * 512 + k0b + cbl,
              Als + i * 4096 + (t & 192) * 16);
      gload16((const char*)WT + (size_t)(nb + row) * 512 + k0b + cbl,
              Bls + i * 4096 + (t & 192) * 16);
    }
    __syncthreads();
#pragma unroll
    for (int ks = 0; ks < 2; ++ks) {
      bf16x8 af[4], bfv[4];
#pragma unroll
      for (int mi = 0; mi < 4; ++mi) {
        int ra = wr * 64 + mi * 16 + lrow;
        int cba = (ks * 64 + lg * 16) ^ ((ra & 7) << 4);
        af[mi] = *(const bf16x8*)(Als + ra * 128 + cba);
        int rb = wc * 64 + mi * 16 + lrow;
        int cbb = (ks * 64 + lg * 16) ^ ((rb & 7) << 4);
        bfv[mi] = *(const bf16x8*)(Bls + rb * 128 + cbb);
      }
#pragma unroll
      for (int mi = 0; mi < 4; ++mi)
#pragma unroll
        for (int ni = 0; ni < 4; ++ni)
          acc[mi][ni] = __builtin_amdgcn_mfma_f32_16x16x32_bf16(af[mi], bfv[ni], acc[mi][ni], 0, 0, 0);
    }
    __syncthreads();
  }

  double ps[4] = {0, 0, 0, 0}, pq[4] = {0, 0, 0, 0};
#pragma unroll
  for (int mi = 0; mi < 4; ++mi) {
#pragma unroll
    for (int r = 0; r < 4; ++r) {
      int m = m0 + wr * 64 + mi * 16 + lg * 4 + r;
      if (MODE == 0 && m >= M) continue;
      int mk = 0;
      if constexpr (MODE == 3) { mk = maskp[m]; }
#pragma unroll
      for (int ni = 0; ni < 4; ++ni) {
        int n = nb + wc * 64 + ni * 16 + lrow;
        float v = acc[mi][ni][r] + bias[n];
        if constexpr (MODE == 0) {
          out_f32[(size_t)m * 1024 + n] = v;
        } else if constexpr (MODE == 2) {
          float r2 = out_f32[(size_t)m * 256 + n] + v;
          out_f32[(size_t)m * 256 + n] = r2;
          out_bf16[(size_t)m * 256 + n] = f2bf(r2);
          if constexpr (GN) {
            ps[ni] += (double)r2;
            pq[ni] += (double)r2 * (double)r2;
          }
        } else {
          v += mask_emb[mk * 256 + n];
          out_f32[(size_t)m * 256 + n] = v;
          out_bf16[(size_t)m * 256 + n] = f2bf(v);
        }
      }
    }
  }

  if constexpr (GN) {
    __syncthreads();
    double* redS = (double*)lds;           // [128][8] f64 = 8KB
    double* redQ = (double*)(lds + 8192);  // 8KB
    int slot = wr * 4 + lg;
#pragma unroll
    for (int ni = 0; ni < 4; ++ni) {
      int cn = wc * 64 + ni * 16 + lrow;
      redS[cn * 8 + slot] = ps[ni];
      redQ[cn * 8 + slot] = pq[ni];
    }
    __syncthreads();
    if (t < 128) {
      double s = 0, q = 0;
#pragma unroll
      for (int k = 0; k < 8; ++k) { s += redS[t * 8 + k]; q += redQ[t * 8 + k]; }
      atomicAdd(&gnp[nb + t], s);
      atomicAdd(&gnp[H + nb + t], q);
    }
  }
}

// ---------------------------------------------------------------------------
// Fused layer-edge kernel v3: BM=32 (2 nodes), BN=256, 8 waves (512 thr).
// LDS = max(A 4K + B 32K, enew 32x256 f32) = 36KB -> 4 blocks/CU (100% waves).
// E0: acc + Cb + Ah[col] + Bh[row] -> enew (XOR-swizzled f32)
// E1: node update (waves 0-1, one node each)
// E2: double-LN+silu -> bout bf16 (all 8 waves, 4 rows each)
// ---------------------------------------------------------------------------
__global__ __launch_bounds__(512, 8) void k_layer_edge(const unsigned short* __restrict__ A,
                                                       const unsigned short* __restrict__ WT,
                                                       const float* __restrict__ Cb,
                                                       const int* __restrict__ ei_col,
                                                       const float* __restrict__ XW,
                                                       const float* __restrict__ nhg, const float* __restrict__ nhb,
                                                       const float* __restrict__ neg_, const float* __restrict__ neb_,
                                                       const float* __restrict__ tvec_l,
                                                       const float* __restrict__ pg_, const float* __restrict__ pb_,
                                                       float* __restrict__ x, unsigned short* __restrict__ xb,
                                                       unsigned short* __restrict__ bout) {
  const int t = threadIdx.x;
  const int m0 = blockIdx.x * 32;
  const int lane = t & 63;
  const int wave = t >> 6;      // 8 col-groups of 32 cols each
  const int wc = wave;
  const int lrow = lane & 15, lg = lane >> 4;
  const int c0 = lane * 4;

  __shared__ __align__(16) char lds[36864];
  char* Als = lds;            // [32][128B] swizzled (GEMM phase)
  char* Bls = lds + 4096;     // [256][128B] swizzled (GEMM phase)
  float* enew = (float*)lds;  // [32][256] f32 swizzled (epilogue)

  f32x4 acc[2][2];
#pragma unroll
  for (int i = 0; i < 2; ++i)
#pragma unroll
    for (int j = 0; j < 2; ++j) acc[i][j] = (f32x4)0.0f;

  const int wave_off = wave * 1024;
  for (int kt = 0; kt < 4; ++kt) {
    const int k0b = kt * 128;
    if (t < 256) {  // A: 32 rows x 128B = 4KB (waves 0-3, one 16B load each)
      int o = t * 16;
      int row = o >> 7;
      int cbl = (o & 127) ^ ((row & 7) << 4);
      gload16((const char*)A + (size_t)(m0 + row) * 512 + k0b + cbl, Als + wave_off);
    }
#pragma unroll
    for (int c = 0; c < 4; ++c) {  // B: 256 rows x 128B = 32KB
      int o = c * 8192 + t * 16;
      int row = o >> 7;
      int cbl = (o & 127) ^ ((row & 7) << 4);
      gload16((const char*)WT + (size_t)row * 512 + k0b + cbl, Bls + c * 8192 + wave_off);
    }
    __syncthreads();
#pragma unroll
    for (int ks = 0; ks < 2; ++ks) {
      bf16x8 af[2], bfv[2];
#pragma unroll
      for (int mi = 0; mi < 2; ++mi) {
        int ra = mi * 16 + lrow;
        af[mi] = *(const bf16x8*)(Als + ra * 128 + ((ks * 64 + lg * 16) ^ ((ra & 7) << 4)));
      }
#pragma unroll
      for (int ni = 0; ni < 2; ++ni) {
        int rb = wc * 32 + ni * 16 + lrow;
        bfv[ni] = *(const bf16x8*)(Bls + rb * 128 + ((ks * 64 + lg * 16) ^ ((rb & 7) << 4)));
      }
#pragma unroll
      for (int mi = 0; mi < 2; ++mi)
#pragma unroll
        for (int ni = 0; ni < 2; ++ni)
          acc[mi][ni] = __builtin_amdgcn_mfma_f32_16x16x32_bf16(af[mi], bfv[ni], acc[mi][ni], 0, 0, 0);
    }
    __syncthreads();
  }

  // ---- E0: acc + Cb + Ah[col] + Bh[node] -> enew (swizzled f32) ----
  {
    float bs[2];
#pragma unroll
    for (int ni = 0; ni < 2; ++ni) bs[ni] = Cb[wc * 32 + ni * 16 + lrow];
#pragma unroll
    for (int mi = 0; mi < 2; ++mi) {
#pragma unroll
      for (int r = 0; r < 4; ++r) {
        int ml = mi * 16 + lg * 4 + r;
        int m = m0 + ml;
        int cv = ei_col[m];
        const float* AhR = XW + (size_t)cv * 1024 + 512;
        const float* BhR = XW + (size_t)(m >> 4) * 1024 + 768;
        int sw = (ml & 15) << 2;
#pragma unroll
        for (int ni = 0; ni < 2; ++ni) {
          int n = wc * 32 + ni * 16 + lrow;
          enew[ml * 256 + (n ^ sw)] = acc[mi][ni][r] + bs[ni] + AhR[n] + BhR[n];
        }
      }
    }
  }
  __syncthreads();

  // ---- E1: node update (waves 0-1, one node each) ----
  if (wave < 2) {
    int v = (m0 >> 4) + wave;
    f32x4 agg = (f32x4)0.0f;
#pragma unroll 4
    for (int k = 0; k < K_DEG; ++k) {
      int row = wave * 16 + k;
      int cv = ei_col[m0 + row];
      f32x4 en = *(const f32x4*)&enew[row * 256 + (c0 ^ ((row & 15) << 2))];
      f32x4 vh = *(const f32x4*)&XW[(size_t)cv * 1024 + 256 + c0];
#pragma unroll
      for (int i = 0; i < 4; ++i) agg[i] += vh[i] * fsig(en[i]);
    }
    f32x4 s4 = *(const f32x4*)&XW[(size_t)v * 1024 + c0];  // Uh
    s4 += agg;
    float s = s4[0] + s4[1] + s4[2] + s4[3];
    float sq = s4[0] * s4[0] + s4[1] * s4[1] + s4[2] * s4[2] + s4[3] * s4[3];
#pragma unroll
    for (int st = 1; st < 64; st <<= 1) { s += __shfl_xor(s, st); sq += __shfl_xor(sq, st); }
    float mean = s * (1.0f / H);
    float inv = rsqrtf(sq * (1.0f / H) - mean * mean + 1e-5f);
    f32x4 g = *(const f32x4*)&nhg[c0];
    f32x4 bb = *(const f32x4*)&nhb[c0];
    f32x4 xo = *(const f32x4*)&x[(size_t)v * H + c0];
    u16x4 ov;
#pragma unroll
    for (int i = 0; i < 4; ++i) {
      float h = fmaxf((s4[i] - mean) * inv * g[i] + bb[i], 0.0f);
      xo[i] += h;
      ov[i] = f2bf(xo[i]);
    }
    *(f32x4*)&x[(size_t)v * H + c0] = xo;
    *(u16x4*)&xb[(size_t)v * H + c0] = ov;
  }

  // ---- E2: double-LN + silu chain -> bout bf16 (4 rows per wave) ----
  {
    f32x4 g1 = *(const f32x4*)&neg_[c0];
    f32x4 b1 = *(const f32x4*)&neb_[c0];
    f32x4 tv = *(const f32x4*)&tvec_l[c0];
    f32x4 g2 = *(const f32x4*)&pg_[c0];
    f32x4 b2 = *(const f32x4*)&pb_[c0];
#pragma unroll
    for (int k = 0; k < 4; ++k) {
      int row = wave + 8 * k;
      f32x4 vv = *(const f32x4*)&enew[row * 256 + (c0 ^ ((row & 15) << 2))];
      float s = vv[0] + vv[1] + vv[2] + vv[3];
      float sq = vv[0] * vv[0] + vv[1] * vv[1] + vv[2] * vv[2] + vv[3] * vv[3];
#pragma unroll
      for (int st = 1; st < 64; st <<= 1) { s += __shfl_xor(s, st); sq += __shfl_xor(sq, st); }
      float mean = s * (1.0f / H);
      float inv = rsqrtf(sq * (1.0f / H) - mean * mean + 1e-5f);
      f32x4 a;
#pragma unroll
      for (int i = 0; i < 4; ++i) a[i] = fmaxf((vv[i] - mean) * inv * g1[i] + b1[i], 0.0f) + tv[i];
      s = a[0] + a[1] + a[2] + a[3];
      sq = a[0] * a[0] + a[1] * a[1] + a[2] * a[2] + a[3] * a[3];
#pragma unroll
      for (int st = 1; st < 64; st <<= 1) { s += __shfl_xor(s, st); sq += __shfl_xor(sq, st); }
      mean = s * (1.0f / H);
      inv = rsqrtf(sq * (1.0f / H) - mean * mean + 1e-5f);
      u16x4 ov;
#pragma unroll
      for (int i = 0; i < 4; ++i) {
        float n = (a[i] - mean) * inv * g2[i] + b2[i];
        ov[i] = f2bf(n * fsig(n));
      }
      *(u16x4*)&bout[(size_t)(m0 + row) * H + c0] = ov;
    }
  }
}

// ---------------------------------------------------------------------------
// Node positional embedding + node_w matmul
// ---------------------------------------------------------------------------
__global__ __launch_bounds__(256) void k_node_embed(const float* __restrict__ coords,
                                                    const float* __restrict__ W,
                                                    const float* __restrict__ b,
                                                    float* __restrict__ x,
                                                    unsigned short* __restrict__ xb) {
  int v = blockIdx.x;
  int j = threadIdx.x;
  __shared__ float4 pe4[H / 4];
  float cy = coords[v * 2 + 0] * 6.283185307179586f;
  float cx = coords[v * 2 + 1] * 6.283185307179586f;
  int idx = j & 127;
  float coord = (j < 128) ? cy : cx;
  float dim_t = powf(10000.0f, (2.0f * (float)(idx >> 1)) / 128.0f);
  float val = coord / dim_t;
  ((float*)pe4)[j] = (idx & 1) ? cosf(val) : sinf(val);
  __syncthreads();
  float acc = b[j];
  for (int k4 = 0; k4 < H / 4; ++k4) {
    float4 p = pe4[k4];
    int k = 4 * k4;
    acc += p.x * W[(k + 0) * H + j] + p.y * W[(k + 1) * H + j] +
           p.z * W[(k + 2) * H + j] + p.w * W[(k + 3) * H + j];
  }
  x[(size_t)v * H + j] = acc;
  xb[(size_t)v * H + j] = f2bf(acc);
}

// ---------------------------------------------------------------------------
// Edge scalar sine embedding -> pe bf16
// ---------------------------------------------------------------------------
__global__ __launch_bounds__(256) void k_pe(const float* __restrict__ e_vals, unsigned short* __restrict__ pe) {
  int eid = blockIdx.x * 4 + (threadIdx.x >> 6);
  int lane = threadIdx.x & 63;
  int c0 = lane * 4;
  float val = e_vals[eid];
  const float lg = 13.287712379549449f / 256.0f;
  u16x4 ov;
#pragma unroll
  for (int i = 0; i < 4; ++i) {
    int c = c0 + i;
    float invd = exp2f(-(float)(c & ~1) * lg);
    float arg = val * invd;
    float s = (c & 1) ? cosf(arg) : sinf(arg);
    ov[i] = f2bf(s);
  }
  *(u16x4*)&pe[(size_t)eid * H + c0] = ov;
}

// ---------------------------------------------------------------------------
// Timestep embedding MLP + per-layer conditioning
// ---------------------------------------------------------------------------
__global__ __launch_bounds__(256) void k_temb(const int* __restrict__ t,
                                              const float* __restrict__ te1_w, const float* __restrict__ te1_b,
                                              const float* __restrict__ te2_w, const float* __restrict__ te2_b,
                                              float* __restrict__ temb_out) {
  __shared__ float emb[H];
  __shared__ float h1[TE];
  int j = threadIdx.x;
  float tv = (float)t[0];
  {
    int i = j & 127;
    float f = expf(-logf(10000.0f) * (float)i / 128.0f);
    float arg = tv * f;
    emb[j] = (j < 128) ? cosf(arg) : sinf(arg);
  }
  __syncthreads();
  if (j < TE) {
    float acc = te1_b[j];
    for (int k = 0; k < H; ++k) acc += emb[k] * te1_w[k * TE + j];
    h1[j] = fmaxf(acc, 0.0f);
  }
  __syncthreads();
  if (j < TE) {
    float acc = te2_b[j];
    for (int k = 0; k < TE; ++k) acc += h1[k] * te2_w[k * TE + j];
    temb_out[j] = acc;
  }
}

__global__ __launch_bounds__(256) void k_tvec(const float* __restrict__ temb,
                                              const float* __restrict__ tl_w, const float* __restrict__ tl_b,
                                              float* __restrict__ tvec) {
  int l = blockIdx.x;
  int j = threadIdx.x;
  __shared__ float rt[TE];
  if (j < TE) rt[j] = fmaxf(temb[j], 0.0f);
  __syncthreads();
  float acc = tl_b[l * H + j];
  for (int k = 0; k < TE; ++k) acc += rt[k] * tl_w[(size_t)(l * TE + k) * H + j];
  tvec[l * H + j] = acc;
}

__global__ void k_gn_finalize(const double* __restrict__ sums, float* __restrict__ gstats) {
  int g = threadIdx.x;
  if (g < 32) {
    double s = 0.0, sq = 0.0;
    for (int c = g * 8; c < g * 8 + 8; ++c) {
      s += sums[c];
      sq += sums[H + c];
    }
    double n = 8.0 * (double)E_EDGES;
    double mean = s / n;
    double var = sq / n - mean * mean;
    gstats[g] = (float)mean;
    gstats[32 + g] = (float)(1.0 / sqrt(var + 1e-5));
  }
}

__global__ __launch_bounds__(256) void k_head(const float* __restrict__ e,
                                              const float* __restrict__ gstats,
                                              const float* __restrict__ gn_g, const float* __restrict__ gn_b,
                                              const float* __restrict__ out_w, const float* __restrict__ out_b,
                                              float* __restrict__ out) {
  int wv = threadIdx.x >> 6;
  int lane = threadIdx.x & 63;
  int eid = blockIdx.x * 4 + wv;
  int c0 = lane * 4;
  float4 ev = *(const float4*)&e[(size_t)eid * H + c0];
  float vv[4] = {ev.x, ev.y, ev.z, ev.w};
  float a0 = 0.0f, a1 = 0.0f;
#pragma unroll
  for (int i = 0; i < 4; ++i) {
    int c = c0 + i;
    int g = c >> 3;
    float v = (vv[i] - gstats[g]) * gstats[32 + g] * gn_g[c] + gn_b[c];
    v = fmaxf(v, 0.0f);
    a0 += v * out_w[c * 2 + 0];
    a1 += v * out_w[c * 2 + 1];
  }
  for (int s = 32; s > 0; s >>= 1) {
    a0 += __shfl_down(a0, s);
    a1 += __shfl_down(a1, s);
  }
  if (lane == 0) {
    out[(size_t)eid * 2 + 0] = a0 + out_b[0];
    out[(size_t)eid * 2 + 1] = a1 + out_b[1];
  }
}

// ---------------------------------------------------------------------------
extern "C" void kernel_launch(void* const* d_in, const int* in_sizes, int n_in,
                              void* d_out, int out_size, void* d_ws, size_t ws_size,
                              hipStream_t stream) {
  const float* nodes_feature = (const float*)d_in[0];
  const float* e_vals = (const float*)d_in[1];
  const int* mask = (const int*)d_in[2];
  const int* t = (const int*)d_in[3];
  const int* edge_index = (const int*)d_in[4];
  const float* node_w = (const float*)d_in[5];
  const float* node_b = (const float*)d_in[6];
  const float* edge_w = (const float*)d_in[7];
  const float* edge_b = (const float*)d_in[8];
  const float* te1_w = (const float*)d_in[9];
  const float* te1_b = (const float*)d_in[10];
  const float* te2_w = (const float*)d_in[11];
  const float* te2_b = (const float*)d_in[12];
  const float* U_w = (const float*)d_in[13];
  const float* U_b = (const float*)d_in[14];
  const float* V_w = (const float*)d_in[15];
  const float* V_b = (const float*)d_in[16];
  const float* A_w = (const float*)d_in[17];
  const float* A_b = (const float*)d_in[18];
  const float* B_w = (const float*)d_in[19];
  const float* B_b = (const float*)d_in[20];
  const float* C_w = (const float*)d_in[21];
  const float* C_b = (const float*)d_in[22];
  const float* nh_g = (const float*)d_in[23];
  const float* nh_b = (const float*)d_in[24];
  const float* ne_g = (const float*)d_in[25];
  const float* ne_b = (const float*)d_in[26];
  const float* tl_w = (const float*)d_in[27];
  const float* tl_b = (const float*)d_in[28];
  const float* plo_g = (const float*)d_in[29];
  const float* plo_b = (const float*)d_in[30];
  const float* plo_w = (const float*)d_in[31];
  const float* plo_b2 = (const float*)d_in[32];
  const float* gn_g = (const float*)d_in[33];
  const float* gn_b = (const float*)d_in[34];
  const float* out_w = (const float*)d_in[35];
  const float* out_b = (const float*)d_in[36];
  const float* mask_emb = (const float*)d_in[37];

  char* wsb = (char*)d_ws;
  size_t off = 0;
  auto alloc = [&](size_t bytes) -> void* {
    void* p = wsb + off;
    off += (bytes + 255) & ~(size_t)255;
    return p;
  };
  double* gn_sums = (double*)alloc(512 * sizeof(double));
  float* XW = (float*)alloc((size_t)V_NODES * 1024 * 4);
  float* e = (float*)alloc((size_t)E_EDGES * H * 4);
  unsigned short* e_bf = (unsigned short*)alloc((size_t)E_EDGES * H * 2);
  unsigned short* pe_b = (unsigned short*)alloc((size_t)E_EDGES * H * 2);
  unsigned short* x_bf = (unsigned short*)alloc((size_t)V_NODES * H * 2);
  unsigned short* WT4 = (unsigned short*)alloc((size_t)L_LAYERS * 1024 * H * 2);
  unsigned short* WTC = (unsigned short*)alloc((size_t)L_LAYERS * H * H * 2);
  unsigned short* WTplo = (unsigned short*)alloc((size_t)L_LAYERS * H * H * 2);
  unsigned short* WTedge = (unsigned short*)alloc((size_t)H * H * 2);
  float* b4 = (float*)alloc((size_t)L_LAYERS * 1024 * 4);
  float* temb = (float*)alloc(TE * 4);
  float* tvec = (float*)alloc((size_t)L_LAYERS * H * 4);
  float* gstats = (float*)alloc(64 * 4);

  const int* ei_col = edge_index + E_EDGES;

  float* x = (float*)d_out;
  float* out2 = (float*)d_out + (size_t)V_NODES * H;

  k_prep_w<<<1168, 256, 0, stream>>>(U_w, V_w, A_w, B_w, C_w, plo_w, edge_w, WT4, WTC, WTplo, WTedge);
  k_prep_b<<<L_LAYERS, 256, 0, stream>>>(U_b, V_b, A_b, B_b, b4);
  k_node_embed<<<V_NODES, 256, 0, stream>>>(nodes_feature, node_w, node_b, x, x_bf);
  k_pe<<<E_EDGES / 4, 256, 0, stream>>>(e_vals, pe_b);
  k_temb<<<1, 256, 0, stream>>>(t, te1_w, te1_b, te2_w, te2_b, temb);
  k_tvec<<<L_LAYERS, 256, 0, stream>>>(temb, tl_w, tl_b, tvec);
  k_gemm<3, false><<<dim3(E_EDGES / 128, 2), 256, 0, stream>>>(pe_b, WTedge, E_EDGES, edge_b, mask, mask_emb,
                                                               e, e_bf, nullptr);
  hipMemsetAsync(gn_sums, 0, 512 * sizeof(double), stream);

  for (int l = 0; l < L_LAYERS; ++l) {
    size_t wo = (size_t)l * H * H;
    size_t bo = (size_t)l * H;
    k_gemm<0, false><<<dim3(24, 8), 256, 0, stream>>>(x_bf, WT4 + (size_t)l * 1024 * H, V_NODES, b4 + l * 1024,
                                                      nullptr, nullptr, XW, nullptr, nullptr);
    k_layer_edge<<<E_EDGES / 32, 512, 0, stream>>>(e_bf, WTC + wo, C_b + bo, ei_col, XW,
                                                   nh_g + bo, nh_b + bo, ne_g + bo, ne_b + bo, tvec + bo,
                                                   plo_g + bo, plo_b + bo, x, x_bf, pe_b);
    if (l == L_LAYERS - 1) {
      k_gemm<2, true><<<dim3(E_EDGES / 128, 2), 256, 0, stream>>>(pe_b, WTplo + wo, E_EDGES, plo_b2 + bo,
                                                                  nullptr, nullptr, e, e_bf, gn_sums);
    } else {
      k_gemm<2, false><<<dim3(E_EDGES / 128, 2), 256, 0, stream>>>(pe_b, WTplo + wo, E_EDGES, plo_b2 + bo,
                                                                   nullptr, nullptr, e, e_bf, nullptr);
    }
  }

  k_gn_finalize<<<1, 64, 0, stream>>>(gn_sums, gstats);
  k_head<<<E_EDGES / 4, 256, 0, stream>>>(e, gstats, gn_g, gn_b, out_w, out_b, out2);
}

// Round 7
// 810.225 us; speedup vs baseline: 1.5799x; 1.2150x over previous
//
#include <hip/hip_runtime.h>
#include <math.h>

#define V_NODES 3000
#define K_DEG 16
#define E_EDGES 48000
#define H 256
#define TE 128
#define L_LAYERS 12

typedef __attribute__((ext_vector_type(4))) float f32x4;
typedef __attribute__((ext_vector_type(8))) __bf16 bf16x8;
typedef __attribute__((ext_vector_type(4))) unsigned short u16x4;

__device__ __forceinline__ unsigned short f2bf(float f) {
  unsigned u = __float_as_uint(f);
  unsigned r = (u + 0x7fffu + ((u >> 16) & 1u)) >> 16;
  return (unsigned short)r;
}

__device__ __forceinline__ float bf2f(unsigned short u) {
  return __uint_as_float(((unsigned)u) << 16);
}

// fast sigmoid: 1/(1+2^(-x*log2e)) via v_exp_f32 + v_rcp_f32 (~1e-6 rel err)
__device__ __forceinline__ float fsig(float x) {
  return __builtin_amdgcn_rcpf(1.0f + __builtin_amdgcn_exp2f(-1.4426950408889634f * x));
}

__device__ __forceinline__ void gload16(const void* g, void* l) {
  __builtin_amdgcn_global_load_lds((const __attribute__((address_space(1))) void*)g,
                                   (__attribute__((address_space(3))) void*)l, 16, 0, 0);
}

// ---------------------------------------------------------------------------
// Weight prep: transpose 256x256 f32 [k][n] -> bf16 [n][k]; UVAB packed to
// [1024][256] per layer.
// ---------------------------------------------------------------------------
__global__ __launch_bounds__(256) void k_prep_w(const float* __restrict__ U_w, const float* __restrict__ V_w,
                                                const float* __restrict__ A_w, const float* __restrict__ B_w,
                                                const float* __restrict__ C_w, const float* __restrict__ plo_w,
                                                const float* __restrict__ edge_w,
                                                unsigned short* __restrict__ WT4, unsigned short* __restrict__ WTC,
                                                unsigned short* __restrict__ WTplo, unsigned short* __restrict__ WTedge) {
  int bid = blockIdx.x;
  const float* src;
  unsigned short* dst;
  int tt;
  if (bid < 768) {
    int l = bid >> 6;
    int rem = bid & 63;
    int mat = rem >> 4;
    tt = rem & 15;
    const float* srcs[4] = {U_w, V_w, A_w, B_w};
    src = srcs[mat] + (size_t)l * H * H;
    dst = WT4 + (size_t)l * 1024 * H + (size_t)mat * H * H;
  } else if (bid < 960) {
    int b2 = bid - 768;
    int l = b2 >> 4;
    tt = b2 & 15;
    src = C_w + (size_t)l * H * H;
    dst = WTC + (size_t)l * H * H;
  } else if (bid < 1152) {
    int b2 = bid - 960;
    int l = b2 >> 4;
    tt = b2 & 15;
    src = plo_w + (size_t)l * H * H;
    dst = WTplo + (size_t)l * H * H;
  } else {
    tt = bid - 1152;
    src = edge_w;
    dst = WTedge;
  }
  int k0 = (tt & 3) * 64, n0 = (tt >> 2) * 64;
  __shared__ float ts[64][65];
  int c = threadIdx.x & 63;
  int r0 = threadIdx.x >> 6;
  for (int rr = 0; rr < 64; rr += 4) {
    int r = rr + r0;
    ts[r][c] = src[(size_t)(k0 + r) * H + n0 + c];
  }
  __syncthreads();
  for (int nn = 0; nn < 64; nn += 4) {
    int n = nn + r0;
    dst[(size_t)(n0 + n) * H + k0 + c] = f2bf(ts[c][n]);
  }
}

__global__ __launch_bounds__(256) void k_prep_b(const float* __restrict__ U_b, const float* __restrict__ V_b,
                                                const float* __restrict__ A_b, const float* __restrict__ B_b,
                                                float* __restrict__ b4) {
  int l = blockIdx.x;
  int t = threadIdx.x;
  b4[l * 1024 + 0 + t] = U_b[l * H + t];
  b4[l * 1024 + 256 + t] = V_b[l * H + t];
  b4[l * 1024 + 512 + t] = A_b[l * H + t];
  b4[l * 1024 + 768 + t] = B_b[l * H + t];
}

// ---------------------------------------------------------------------------
// Plain MFMA GEMM (128x128 tile, 4 waves, BK=64).
// MODE 0: node UVAB -> out_f32[m*1024+n] = acc + bias[n]
// MODE 2: edge plo  -> e_bf += acc + bias (bf16 storage); GN: fused stats
// MODE 3: edge embed-> acc + bias + mask_emb[mask[m]] -> e_bf
// ---------------------------------------------------------------------------
template <int MODE, bool GN>
__global__ __launch_bounds__(256) void k_gemm(const unsigned short* __restrict__ A,
                                              const unsigned short* __restrict__ WT,
                                              int M,
                                              const float* __restrict__ bias,
                                              const int* __restrict__ maskp,
                                              const float* __restrict__ mask_emb,
                                              float* __restrict__ out_f32,
                                              unsigned short* __restrict__ out_bf16,
                                              double* __restrict__ gnp) {
  const int t = threadIdx.x;
  const int m0 = blockIdx.x * 128;
  const int nb = blockIdx.y * 128;
  const int lane = t & 63;
  const int wave = t >> 6;
  const int wr = wave >> 1, wc = wave & 1;
  const int lrow = lane & 15, lg = lane >> 4;

  __shared__ __align__(16) char lds[32768];
  char* Als = lds;
  char* Bls = lds + 16384;

  f32x4 acc[4][4];
#pragma unroll
  for (int i = 0; i < 4; ++i)
#pragma unroll
    for (int j = 0; j < 4; ++j) acc[i][j] = (f32x4)0.0f;

  for (int kt = 0; kt < 4; ++kt) {
    const int k0b = kt * 128;
#pragma unroll
    for (int i = 0; i < 4; ++i) {
      int o = i * 4096 + t * 16;
      int row = o >> 7;
      int cb = o & 127;
      int cbl = cb ^ ((row & 7) << 4);
      int rA = m0 + row;
      rA = rA < M ? rA : 0;
      gload16((const char*)A + (size_t)rA * 512 + k0b + cbl,
              Als + i * 4096 + (t & 192) * 16);
      gload16((const char*)WT + (size_t)(nb + row) * 512 + k0b + cbl,
              Bls + i * 4096 + (t & 192) * 16);
    }
    __syncthreads();
#pragma unroll
    for (int ks = 0; ks < 2; ++ks) {
      bf16x8 af[4], bfv[4];
#pragma unroll
      for (int mi = 0; mi < 4; ++mi) {
        int ra = wr * 64 + mi * 16 + lrow;
        int cba = (ks * 64 + lg * 16) ^ ((ra & 7) << 4);
        af[mi] = *(const bf16x8*)(Als + ra * 128 + cba);
        int rb = wc * 64 + mi * 16 + lrow;
        int cbb = (ks * 64 + lg * 16) ^ ((rb & 7) << 4);
        bfv[mi] = *(const bf16x8*)(Bls + rb * 128 + cbb);
      }
#pragma unroll
      for (int mi = 0; mi < 4; ++mi)
#pragma unroll
        for (int ni = 0; ni < 4; ++ni)
          acc[mi][ni] = __builtin_amdgcn_mfma_f32_16x16x32_bf16(af[mi], bfv[ni], acc[mi][ni], 0, 0, 0);
    }
    __syncthreads();
  }

  double ps[4] = {0, 0, 0, 0}, pq[4] = {0, 0, 0, 0};
#pragma unroll
  for (int mi = 0; mi < 4; ++mi) {
#pragma unroll
    for (int r = 0; r < 4; ++r) {
      int m = m0 + wr * 64 + mi * 16 + lg * 4 + r;
      if (MODE == 0 && m >= M) continue;
      int mk = 0;
      if constexpr (MODE == 3) { mk = maskp[m]; }
#pragma unroll
      for (int ni = 0; ni < 4; ++ni) {
        int n = nb + wc * 64 + ni * 16 + lrow;
        float v = acc[mi][ni][r] + bias[n];
        if constexpr (MODE == 0) {
          out_f32[(size_t)m * 1024 + n] = v;
        } else if constexpr (MODE == 2) {
          float eo = bf2f(out_bf16[(size_t)m * 256 + n]);
          unsigned short nb16 = f2bf(eo + v);
          out_bf16[(size_t)m * 256 + n] = nb16;
          if constexpr (GN) {
            float rv = bf2f(nb16);
            ps[ni] += (double)rv;
            pq[ni] += (double)rv * (double)rv;
          }
        } else {
          v += mask_emb[mk * 256 + n];
          out_bf16[(size_t)m * 256 + n] = f2bf(v);
        }
      }
    }
  }

  if constexpr (GN) {
    __syncthreads();
    double* redS = (double*)lds;           // [128][8] f64 = 8KB
    double* redQ = (double*)(lds + 8192);  // 8KB
    int slot = wr * 4 + lg;
#pragma unroll
    for (int ni = 0; ni < 4; ++ni) {
      int cn = wc * 64 + ni * 16 + lrow;
      redS[cn * 8 + slot] = ps[ni];
      redQ[cn * 8 + slot] = pq[ni];
    }
    __syncthreads();
    if (t < 128) {
      double s = 0, q = 0;
#pragma unroll
      for (int k = 0; k < 8; ++k) { s += redS[t * 8 + k]; q += redQ[t * 8 + k]; }
      atomicAdd(&gnp[nb + t], s);
      atomicAdd(&gnp[H + nb + t], q);
    }
  }
}

// ---------------------------------------------------------------------------
// Fused layer-edge kernel v3: BM=32 (2 nodes), BN=256, 8 waves (512 thr).
// LDS = max(A 4K + B 32K, enew 32x256 f32) = 36KB -> 4 blocks/CU (100% waves).
// E0: acc + Cb + Ah[col] + Bh[row] -> enew (XOR-swizzled f32)
// E1: node update (waves 0-1, one node each)
// E2: double-LN+silu -> bout bf16 (all 8 waves, 4 rows each)
// ---------------------------------------------------------------------------
__global__ __launch_bounds__(512, 8) void k_layer_edge(const unsigned short* __restrict__ A,
                                                       const unsigned short* __restrict__ WT,
                                                       const float* __restrict__ Cb,
                                                       const int* __restrict__ ei_col,
                                                       const float* __restrict__ XW,
                                                       const float* __restrict__ nhg, const float* __restrict__ nhb,
                                                       const float* __restrict__ neg_, const float* __restrict__ neb_,
                                                       const float* __restrict__ tvec_l,
                                                       const float* __restrict__ pg_, const float* __restrict__ pb_,
                                                       float* __restrict__ x, unsigned short* __restrict__ xb,
                                                       unsigned short* __restrict__ bout) {
  const int t = threadIdx.x;
  const int m0 = blockIdx.x * 32;
  const int lane = t & 63;
  const int wave = t >> 6;      // 8 col-groups of 32 cols each
  const int wc = wave;
  const int lrow = lane & 15, lg = lane >> 4;
  const int c0 = lane * 4;

  __shared__ __align__(16) char lds[36864];
  char* Als = lds;            // [32][128B] swizzled (GEMM phase)
  char* Bls = lds + 4096;     // [256][128B] swizzled (GEMM phase)
  float* enew = (float*)lds;  // [32][256] f32 swizzled (epilogue)

  f32x4 acc[2][2];
#pragma unroll
  for (int i = 0; i < 2; ++i)
#pragma unroll
    for (int j = 0; j < 2; ++j) acc[i][j] = (f32x4)0.0f;

  const int wave_off = wave * 1024;
  for (int kt = 0; kt < 4; ++kt) {
    const int k0b = kt * 128;
    if (t < 256) {  // A: 32 rows x 128B = 4KB (waves 0-3, one 16B load each)
      int o = t * 16;
      int row = o >> 7;
      int cbl = (o & 127) ^ ((row & 7) << 4);
      gload16((const char*)A + (size_t)(m0 + row) * 512 + k0b + cbl, Als + wave_off);
    }
#pragma unroll
    for (int c = 0; c < 4; ++c) {  // B: 256 rows x 128B = 32KB
      int o = c * 8192 + t * 16;
      int row = o >> 7;
      int cbl = (o & 127) ^ ((row & 7) << 4);
      gload16((const char*)WT + (size_t)row * 512 + k0b + cbl, Bls + c * 8192 + wave_off);
    }
    __syncthreads();
#pragma unroll
    for (int ks = 0; ks < 2; ++ks) {
      bf16x8 af[2], bfv[2];
#pragma unroll
      for (int mi = 0; mi < 2; ++mi) {
        int ra = mi * 16 + lrow;
        af[mi] = *(const bf16x8*)(Als + ra * 128 + ((ks * 64 + lg * 16) ^ ((ra & 7) << 4)));
      }
#pragma unroll
      for (int ni = 0; ni < 2; ++ni) {
        int rb = wc * 32 + ni * 16 + lrow;
        bfv[ni] = *(const bf16x8*)(Bls + rb * 128 + ((ks * 64 + lg * 16) ^ ((rb & 7) << 4)));
      }
#pragma unroll
      for (int mi = 0; mi < 2; ++mi)
#pragma unroll
        for (int ni = 0; ni < 2; ++ni)
          acc[mi][ni] = __builtin_amdgcn_mfma_f32_16x16x32_bf16(af[mi], bfv[ni], acc[mi][ni], 0, 0, 0);
    }
    __syncthreads();
  }

  // ---- E0: acc + Cb + Ah[col] + Bh[node] -> enew (swizzled f32) ----
  {
    float bs[2];
#pragma unroll
    for (int ni = 0; ni < 2; ++ni) bs[ni] = Cb[wc * 32 + ni * 16 + lrow];
#pragma unroll
    for (int mi = 0; mi < 2; ++mi) {
#pragma unroll
      for (int r = 0; r < 4; ++r) {
        int ml = mi * 16 + lg * 4 + r;
        int m = m0 + ml;
        int cv = ei_col[m];
        const float* AhR = XW + (size_t)cv * 1024 + 512;
        const float* BhR = XW + (size_t)(m >> 4) * 1024 + 768;
        int sw = (ml & 15) << 2;
#pragma unroll
        for (int ni = 0; ni < 2; ++ni) {
          int n = wc * 32 + ni * 16 + lrow;
          enew[ml * 256 + (n ^ sw)] = acc[mi][ni][r] + bs[ni] + AhR[n] + BhR[n];
        }
      }
    }
  }
  __syncthreads();

  // ---- E1: node update (waves 0-1, one node each) ----
  if (wave < 2) {
    int v = (m0 >> 4) + wave;
    f32x4 agg = (f32x4)0.0f;
#pragma unroll 4
    for (int k = 0; k < K_DEG; ++k) {
      int row = wave * 16 + k;
      int cv = ei_col[m0 + row];
      f32x4 en = *(const f32x4*)&enew[row * 256 + (c0 ^ ((row & 15) << 2))];
      f32x4 vh = *(const f32x4*)&XW[(size_t)cv * 1024 + 256 + c0];
#pragma unroll
      for (int i = 0; i < 4; ++i) agg[i] += vh[i] * fsig(en[i]);
    }
    f32x4 s4 = *(const f32x4*)&XW[(size_t)v * 1024 + c0];  // Uh
    s4 += agg;
    float s = s4[0] + s4[1] + s4[2] + s4[3];
    float sq = s4[0] * s4[0] + s4[1] * s4[1] + s4[2] * s4[2] + s4[3] * s4[3];
#pragma unroll
    for (int st = 1; st < 64; st <<= 1) { s += __shfl_xor(s, st); sq += __shfl_xor(sq, st); }
    float mean = s * (1.0f / H);
    float inv = rsqrtf(sq * (1.0f / H) - mean * mean + 1e-5f);
    f32x4 g = *(const f32x4*)&nhg[c0];
    f32x4 bb = *(const f32x4*)&nhb[c0];
    f32x4 xo = *(const f32x4*)&x[(size_t)v * H + c0];
    u16x4 ov;
#pragma unroll
    for (int i = 0; i < 4; ++i) {
      float h = fmaxf((s4[i] - mean) * inv * g[i] + bb[i], 0.0f);
      xo[i] += h;
      ov[i] = f2bf(xo[i]);
    }
    *(f32x4*)&x[(size_t)v * H + c0] = xo;
    *(u16x4*)&xb[(size_t)v * H + c0] = ov;
  }

  // ---- E2: double-LN + silu chain -> bout bf16 (4 rows per wave) ----
  {
    f32x4 g1 = *(const f32x4*)&neg_[c0];
    f32x4 b1 = *(const f32x4*)&neb_[c0];
    f32x4 tv = *(const f32x4*)&tvec_l[c0];
    f32x4 g2 = *(const f32x4*)&pg_[c0];
    f32x4 b2 = *(const f32x4*)&pb_[c0];
#pragma unroll
    for (int k = 0; k < 4; ++k) {
      int row = wave + 8 * k;
      f32x4 vv = *(const f32x4*)&enew[row * 256 + (c0 ^ ((row & 15) << 2))];
      float s = vv[0] + vv[1] + vv[2] + vv[3];
      float sq = vv[0] * vv[0] + vv[1] * vv[1] + vv[2] * vv[2] + vv[3] * vv[3];
#pragma unroll
      for (int st = 1; st < 64; st <<= 1) { s += __shfl_xor(s, st); sq += __shfl_xor(sq, st); }
      float mean = s * (1.0f / H);
      float inv = rsqrtf(sq * (1.0f / H) - mean * mean + 1e-5f);
      f32x4 a;
#pragma unroll
      for (int i = 0; i < 4; ++i) a[i] = fmaxf((vv[i] - mean) * inv * g1[i] + b1[i], 0.0f) + tv[i];
      s = a[0] + a[1] + a[2] + a[3];
      sq = a[0] * a[0] + a[1] * a[1] + a[2] * a[2] + a[3] * a[3];
#pragma unroll
      for (int st = 1; st < 64; st <<= 1) { s += __shfl_xor(s, st); sq += __shfl_xor(sq, st); }
      mean = s * (1.0f / H);
      inv = rsqrtf(sq * (1.0f / H) - mean * mean + 1e-5f);
      u16x4 ov;
#pragma unroll
      for (int i = 0; i < 4; ++i) {
        float n = (a[i] - mean) * inv * g2[i] + b2[i];
        ov[i] = f2bf(n * fsig(n));
      }
      *(u16x4*)&bout[(size_t)(m0 + row) * H + c0] = ov;
    }
  }
}

// ---------------------------------------------------------------------------
// Node positional embedding + node_w matmul
// ---------------------------------------------------------------------------
__global__ __launch_bounds__(256) void k_node_embed(const float* __restrict__ coords,
                                                    const float* __restrict__ W,
                                                    const float* __restrict__ b,
                                                    float* __restrict__ x,
                                                    unsigned short* __restrict__ xb) {
  int v = blockIdx.x;
  int j = threadIdx.x;
  __shared__ float4 pe4[H / 4];
  float cy = coords[v * 2 + 0] * 6.283185307179586f;
  float cx = coords[v * 2 + 1] * 6.283185307179586f;
  int idx = j & 127;
  float coord = (j < 128) ? cy : cx;
  float dim_t = powf(10000.0f, (2.0f * (float)(idx >> 1)) / 128.0f);
  float val = coord / dim_t;
  ((float*)pe4)[j] = (idx & 1) ? cosf(val) : sinf(val);
  __syncthreads();
  float acc = b[j];
  for (int k4 = 0; k4 < H / 4; ++k4) {
    float4 p = pe4[k4];
    int k = 4 * k4;
    acc += p.x * W[(k + 0) * H + j] + p.y * W[(k + 1) * H + j] +
           p.z * W[(k + 2) * H + j] + p.w * W[(k + 3) * H + j];
  }
  x[(size_t)v * H + j] = acc;
  xb[(size_t)v * H + j] = f2bf(acc);
}

// ---------------------------------------------------------------------------
// Edge scalar sine embedding -> pe bf16
// ---------------------------------------------------------------------------
__global__ __launch_bounds__(256) void k_pe(const float* __restrict__ e_vals, unsigned short* __restrict__ pe) {
  int eid = blockIdx.x * 4 + (threadIdx.x >> 6);
  int lane = threadIdx.x & 63;
  int c0 = lane * 4;
  float val = e_vals[eid];
  const float lg = 13.287712379549449f / 256.0f;
  u16x4 ov;
#pragma unroll
  for (int i = 0; i < 4; ++i) {
    int c = c0 + i;
    float invd = exp2f(-(float)(c & ~1) * lg);
    float arg = val * invd;
    float s = (c & 1) ? cosf(arg) : sinf(arg);
    ov[i] = f2bf(s);
  }
  *(u16x4*)&pe[(size_t)eid * H + c0] = ov;
}

// ---------------------------------------------------------------------------
// Timestep embedding MLP + per-layer conditioning
// ---------------------------------------------------------------------------
__global__ __launch_bounds__(256) void k_temb(const int* __restrict__ t,
                                              const float* __restrict__ te1_w, const float* __restrict__ te1_b,
                                              const float* __restrict__ te2_w, const float* __restrict__ te2_b,
                                              float* __restrict__ temb_out) {
  __shared__ float emb[H];
  __shared__ float h1[TE];
  int j = threadIdx.x;
  float tv = (float)t[0];
  {
    int i = j & 127;
    float f = expf(-logf(10000.0f) * (float)i / 128.0f);
    float arg = tv * f;
    emb[j] = (j < 128) ? cosf(arg) : sinf(arg);
  }
  __syncthreads();
  if (j < TE) {
    float acc = te1_b[j];
    for (int k = 0; k < H; ++k) acc += emb[k] * te1_w[k * TE + j];
    h1[j] = fmaxf(acc, 0.0f);
  }
  __syncthreads();
  if (j < TE) {
    float acc = te2_b[j];
    for (int k = 0; k < TE; ++k) acc += h1[k] * te2_w[k * TE + j];
    temb_out[j] = acc;
  }
}

__global__ __launch_bounds__(256) void k_tvec(const float* __restrict__ temb,
                                              const float* __restrict__ tl_w, const float* __restrict__ tl_b,
                                              float* __restrict__ tvec) {
  int l = blockIdx.x;
  int j = threadIdx.x;
  __shared__ float rt[TE];
  if (j < TE) rt[j] = fmaxf(temb[j], 0.0f);
  __syncthreads();
  float acc = tl_b[l * H + j];
  for (int k = 0; k < TE; ++k) acc += rt[k] * tl_w[(size_t)(l * TE + k) * H + j];
  tvec[l * H + j] = acc;
}

__global__ void k_gn_finalize(const double* __restrict__ sums, float* __restrict__ gstats) {
  int g = threadIdx.x;
  if (g < 32) {
    double s = 0.0, sq = 0.0;
    for (int c = g * 8; c < g * 8 + 8; ++c) {
      s += sums[c];
      sq += sums[H + c];
    }
    double n = 8.0 * (double)E_EDGES;
    double mean = s / n;
    double var = sq / n - mean * mean;
    gstats[g] = (float)mean;
    gstats[32 + g] = (float)(1.0 / sqrt(var + 1e-5));
  }
}

__global__ __launch_bounds__(256) void k_head(const unsigned short* __restrict__ e_bf,
                                              const float* __restrict__ gstats,
                                              const float* __restrict__ gn_g, const float* __restrict__ gn_b,
                                              const float* __restrict__ out_w, const float* __restrict__ out_b,
                                              float* __restrict__ out) {
  int wv = threadIdx.x >> 6;
  int lane = threadIdx.x & 63;
  int eid = blockIdx.x * 4 + wv;
  int c0 = lane * 4;
  u16x4 ev = *(const u16x4*)&e_bf[(size_t)eid * H + c0];
  float a0 = 0.0f, a1 = 0.0f;
#pragma unroll
  for (int i = 0; i < 4; ++i) {
    int c = c0 + i;
    int g = c >> 3;
    float v = (bf2f(ev[i]) - gstats[g]) * gstats[32 + g] * gn_g[c] + gn_b[c];
    v = fmaxf(v, 0.0f);
    a0 += v * out_w[c * 2 + 0];
    a1 += v * out_w[c * 2 + 1];
  }
  for (int s = 32; s > 0; s >>= 1) {
    a0 += __shfl_down(a0, s);
    a1 += __shfl_down(a1, s);
  }
  if (lane == 0) {
    out[(size_t)eid * 2 + 0] = a0 + out_b[0];
    out[(size_t)eid * 2 + 1] = a1 + out_b[1];
  }
}

// ---------------------------------------------------------------------------
extern "C" void kernel_launch(void* const* d_in, const int* in_sizes, int n_in,
                              void* d_out, int out_size, void* d_ws, size_t ws_size,
                              hipStream_t stream) {
  const float* nodes_feature = (const float*)d_in[0];
  const float* e_vals = (const float*)d_in[1];
  const int* mask = (const int*)d_in[2];
  const int* t = (const int*)d_in[3];
  const int* edge_index = (const int*)d_in[4];
  const float* node_w = (const float*)d_in[5];
  const float* node_b = (const float*)d_in[6];
  const float* edge_w = (const float*)d_in[7];
  const float* edge_b = (const float*)d_in[8];
  const float* te1_w = (const float*)d_in[9];
  const float* te1_b = (const float*)d_in[10];
  const float* te2_w = (const float*)d_in[11];
  const float* te2_b = (const float*)d_in[12];
  const float* U_w = (const float*)d_in[13];
  const float* U_b = (const float*)d_in[14];
  const float* V_w = (const float*)d_in[15];
  const float* V_b = (const float*)d_in[16];
  const float* A_w = (const float*)d_in[17];
  const float* A_b = (const float*)d_in[18];
  const float* B_w = (const float*)d_in[19];
  const float* B_b = (const float*)d_in[20];
  const float* C_w = (const float*)d_in[21];
  const float* C_b = (const float*)d_in[22];
  const float* nh_g = (const float*)d_in[23];
  const float* nh_b = (const float*)d_in[24];
  const float* ne_g = (const float*)d_in[25];
  const float* ne_b = (const float*)d_in[26];
  const float* tl_w = (const float*)d_in[27];
  const float* tl_b = (const float*)d_in[28];
  const float* plo_g = (const float*)d_in[29];
  const float* plo_b = (const float*)d_in[30];
  const float* plo_w = (const float*)d_in[31];
  const float* plo_b2 = (const float*)d_in[32];
  const float* gn_g = (const float*)d_in[33];
  const float* gn_b = (const float*)d_in[34];
  const float* out_w = (const float*)d_in[35];
  const float* out_b = (const float*)d_in[36];
  const float* mask_emb = (const float*)d_in[37];

  char* wsb = (char*)d_ws;
  size_t off = 0;
  auto alloc = [&](size_t bytes) -> void* {
    void* p = wsb + off;
    off += (bytes + 255) & ~(size_t)255;
    return p;
  };
  double* gn_sums = (double*)alloc(512 * sizeof(double));
  float* XW = (float*)alloc((size_t)V_NODES * 1024 * 4);
  unsigned short* e_bf = (unsigned short*)alloc((size_t)E_EDGES * H * 2);
  unsigned short* pe_b = (unsigned short*)alloc((size_t)E_EDGES * H * 2);
  unsigned short* x_bf = (unsigned short*)alloc((size_t)V_NODES * H * 2);
  unsigned short* WT4 = (unsigned short*)alloc((size_t)L_LAYERS * 1024 * H * 2);
  unsigned short* WTC = (unsigned short*)alloc((size_t)L_LAYERS * H * H * 2);
  unsigned short* WTplo = (unsigned short*)alloc((size_t)L_LAYERS * H * H * 2);
  unsigned short* WTedge = (unsigned short*)alloc((size_t)H * H * 2);
  float* b4 = (float*)alloc((size_t)L_LAYERS * 1024 * 4);
  float* temb = (float*)alloc(TE * 4);
  float* tvec = (float*)alloc((size_t)L_LAYERS * H * 4);
  float* gstats = (float*)alloc(64 * 4);

  const int* ei_col = edge_index + E_EDGES;

  float* x = (float*)d_out;
  float* out2 = (float*)d_out + (size_t)V_NODES * H;

  k_prep_w<<<1168, 256, 0, stream>>>(U_w, V_w, A_w, B_w, C_w, plo_w, edge_w, WT4, WTC, WTplo, WTedge);
  k_prep_b<<<L_LAYERS, 256, 0, stream>>>(U_b, V_b, A_b, B_b, b4);
  k_node_embed<<<V_NODES, 256, 0, stream>>>(nodes_feature, node_w, node_b, x, x_bf);
  k_pe<<<E_EDGES / 4, 256, 0, stream>>>(e_vals, pe_b);
  k_temb<<<1, 256, 0, stream>>>(t, te1_w, te1_b, te2_w, te2_b, temb);
  k_tvec<<<L_LAYERS, 256, 0, stream>>>(temb, tl_w, tl_b, tvec);
  k_gemm<3, false><<<dim3(E_EDGES / 128, 2), 256, 0, stream>>>(pe_b, WTedge, E_EDGES, edge_b, mask, mask_emb,
                                                               nullptr, e_bf, nullptr);
  hipMemsetAsync(gn_sums, 0, 512 * sizeof(double), stream);

  for (int l = 0; l < L_LAYERS; ++l) {
    size_t wo = (size_t)l * H * H;
    size_t bo = (size_t)l * H;
    k_gemm<0, false><<<dim3(24, 8), 256, 0, stream>>>(x_bf, WT4 + (size_t)l * 1024 * H, V_NODES, b4 + l * 1024,
                                                      nullptr, nullptr, XW, nullptr, nullptr);
    k_layer_edge<<<E_EDGES / 32, 512, 0, stream>>>(e_bf, WTC + wo, C_b + bo, ei_col, XW,
                                                   nh_g + bo, nh_b + bo, ne_g + bo, ne_b + bo, tvec + bo,
                                                   plo_g + bo, plo_b + bo, x, x_bf, pe_b);
    if (l == L_LAYERS - 1) {
      k_gemm<2, true><<<dim3(E_EDGES / 128, 2), 256, 0, stream>>>(pe_b, WTplo + wo, E_EDGES, plo_b2 + bo,
                                                                  nullptr, nullptr, nullptr, e_bf, gn_sums);
    } else {
      k_gemm<2, false><<<dim3(E_EDGES / 128, 2), 256, 0, stream>>>(pe_b, WTplo + wo, E_EDGES, plo_b2 + bo,
                                                                   nullptr, nullptr, nullptr, e_bf, nullptr);
    }
  }

  k_gn_finalize<<<1, 64, 0, stream>>>(gn_sums, gstats);
  k_head<<<E_EDGES / 4, 256, 0, stream>>>(e_bf, gstats, gn_g, gn_b, out_w, out_b, out2);
}